// Round 3
// baseline (891.071 us; speedup 1.0000x reference)
//
#include <hip/hip_runtime.h>
#include <hip/hip_bf16.h>

typedef __bf16 bf16x8 __attribute__((ext_vector_type(8)));
typedef float f32x4 __attribute__((ext_vector_type(4)));
typedef unsigned short u16x4 __attribute__((ext_vector_type(4)));
typedef unsigned short u16x8 __attribute__((ext_vector_type(8)));

#define DEVI __device__ __forceinline__

constexpr int N_TOK = 2048;   // B*T
constexpr int DIM   = 2048;   // D
constexpr int NEXP  = 64;     // E
constexpr int FDIM  = 512;    // F
constexpr int TOPK  = 4;      // K
constexpr int NSH   = 2;      // S
constexpr int HSH   = 2048;   // HS

constexpr int BM = 128, BN = 128, BK = 64, KS = 8;

DEVI unsigned short f2b(float f) {
  union { float fv; unsigned u; } v; v.fv = f;
  unsigned r = v.u + 0x7fffu + ((v.u >> 16) & 1u);
  return (unsigned short)(r >> 16);
}
DEVI float b2f(unsigned short h) {
  union { unsigned u; float f; } v; v.u = ((unsigned)h) << 16;
  return v.f;
}
DEVI void gll16(const void* g, void* l) {
  __builtin_amdgcn_global_load_lds((const __attribute__((address_space(1))) unsigned*)g,
                                   (__attribute__((address_space(3))) unsigned*)l, 16, 0, 0);
}

// ---------------- x -> bf16 ----------------
__global__ void cvt_x_kernel(const float* __restrict__ x, unsigned short* __restrict__ xb) {
  const size_t i = ((size_t)blockIdx.x * 256 + threadIdx.x) * 8;
  const float4 a = *reinterpret_cast<const float4*>(x + i);
  const float4 b = *reinterpret_cast<const float4*>(x + i + 4);
  u16x8 o;
  o[0] = f2b(a.x); o[1] = f2b(a.y); o[2] = f2b(a.z); o[3] = f2b(a.w);
  o[4] = f2b(b.x); o[5] = f2b(b.y); o[6] = f2b(b.z); o[7] = f2b(b.w);
  *reinterpret_cast<u16x8*>(xb + i) = o;
}

// ---------------- shared weights: transpose + bf16 ----------------
__global__ __launch_bounds__(256)
void tr_shared_kernel(const float* __restrict__ swu, const float* __restrict__ swg,
                      const float* __restrict__ swd, unsigned short* __restrict__ swuT,
                      unsigned short* __restrict__ swgT, unsigned short* __restrict__ swdT) {
  __shared__ float Lf[64][68];
  const int tid = threadIdx.x;
  const int r0 = blockIdx.x * 64, c0 = blockIdx.y * 64;
  const int z = blockIdx.z, mat = z >> 1;
  const size_t soff = (size_t)(z & 1) * DIM * HSH;
  const float* in = (mat == 0 ? swu : mat == 1 ? swg : swd) + soff;
  unsigned short* ot = (mat == 0 ? swuT : mat == 1 ? swgT : swdT) + soff;
  #pragma unroll
  for (int j = 0; j < 4; ++j) {
    const int idx = j * 1024 + tid * 4;
    const int row = idx >> 6, col = idx & 63;
    const float4 v = *reinterpret_cast<const float4*>(in + (size_t)(r0 + row) * 2048 + c0 + col);
    *reinterpret_cast<float4*>(&Lf[row][col]) = v;
  }
  __syncthreads();
  #pragma unroll
  for (int j = 0; j < 4; ++j) {
    const int idx = j * 1024 + tid * 4;
    const int orow = idx >> 6, ocol = idx & 63;
    u16x4 o;
    o[0] = f2b(Lf[ocol][orow]);     o[1] = f2b(Lf[ocol + 1][orow]);
    o[2] = f2b(Lf[ocol + 2][orow]); o[3] = f2b(Lf[ocol + 3][orow]);
    *reinterpret_cast<u16x4*>(ot + (size_t)(c0 + orow) * 2048 + r0 + ocol) = o;
  }
}

// ---------------- Router ----------------
__global__ void router_kernel(const float* __restrict__ x, const float* __restrict__ rw,
                              const float* __restrict__ rb, int* __restrict__ cnt,
                              int* __restrict__ listTok, float* __restrict__ listW) {
  const int lane = threadIdx.x & 63;
  const int wave = threadIdx.x >> 6;
  const int tokBase = blockIdx.x * 8 + wave * 2;
  const float* __restrict__ xr0 = x + (size_t)tokBase * DIM;
  const float* __restrict__ xr1 = xr0 + DIM;
  float acc0 = 0.f, acc1 = 0.f;
  for (int d = 0; d < DIM; ++d) {
    const float r = rw[(size_t)d * NEXP + lane];
    acc0 = fmaf(xr0[d], r, acc0);
    acc1 = fmaf(xr1[d], r, acc1);
  }
  const float bias = rb[lane];
  #pragma unroll
  for (int t = 0; t < 2; ++t) {
    const float v = (t == 0) ? acc0 : acc1;
    const int token = tokBase + t;
    float m = v;
    #pragma unroll
    for (int o = 32; o > 0; o >>= 1) m = fmaxf(m, __shfl_xor(m, o));
    const float p = expf(v - m);
    float ss = p;
    #pragma unroll
    for (int o = 32; o > 0; o >>= 1) ss += __shfl_xor(ss, o);
    const float score = p / ss;
    float cur = v + bias;
    float wk[TOPK]; int ik[TOPK]; float wsum = 0.f;
    #pragma unroll
    for (int k = 0; k < TOPK; ++k) {
      float tm = cur;
      #pragma unroll
      for (int o = 32; o > 0; o >>= 1) tm = fmaxf(tm, __shfl_xor(tm, o));
      const unsigned long long msk = __ballot(cur == tm);
      const int sel = (int)__builtin_ctzll(msk);
      const float w = __shfl(score, sel);
      wk[k] = w; ik[k] = sel; wsum += w;
      if (lane == sel) cur = -3.4e38f;
    }
    if (lane < TOPK) {
      const int e = ik[lane];
      const float w = wk[lane] / wsum;
      const int slot = atomicAdd(&cnt[e], 1);
      listTok[(size_t)e * N_TOK + slot] = token;
      listW[(size_t)e * N_TOK + slot] = w;
    }
  }
}

__global__ void scan_kernel(const int* __restrict__ cnt, int* __restrict__ off) {
  if (threadIdx.x == 0) {
    int s = 0;
    for (int e = 0; e < NEXP; ++e) { off[e] = s; s += cnt[e]; }
  }
}

// ---------------- Unified GEMM ----------------
// MODE 0: U = A @ W            (write U bf16 into Hio)
// MODE 1: G = A @ W; H = silu(G)*U*wS  (read U from Hio, overwrite in place)
// MODE 2: out (+)= H @ Wd      (ROUTED: atomicAdd scatter; shared: direct store, 2 segs)
template<int MODE, bool ROUTED>
__global__ void gemm_kernel(const unsigned short* __restrict__ Ab,
                            const float* __restrict__ Bf,
                            const unsigned short* __restrict__ Bt,
                            const int* __restrict__ cnt, const int* __restrict__ off,
                            const int* __restrict__ listTok, const float* __restrict__ listW,
                            unsigned short* __restrict__ Hio, float* __restrict__ outF) {
  constexpr int KSEG = (MODE < 2) ? DIM : (ROUTED ? FDIM : HSH);
  constexpr int NSEG = (MODE == 2 && !ROUTED) ? NSH : 1;
  constexpr int NOUT = (MODE < 2) ? (ROUTED ? FDIM : HSH) : DIM;
  constexpr int BSTR = (MODE < 2) ? FDIM : DIM;   // f32 weight row stride (routed)
  constexpr int NT = KSEG / BK, TOT = NSEG * NT;

  const int tid = threadIdx.x;
  const int x0 = blockIdx.x * BN;
  const int e  = blockIdx.y;
  const int m0 = blockIdx.z * BM;

  int rcnt = BM, rowbase;
  if constexpr (ROUTED) {
    const int c = cnt[e];
    if (m0 >= c) return;
    rcnt = min(BM, c - m0);
    rowbase = off[e] + m0;
  } else {
    rowbase = (MODE < 2) ? (e * N_TOK + m0) : m0;
  }

  __shared__ __align__(16) unsigned short Al[2][KS][BM][8];
  __shared__ __align__(16) unsigned short Bl[2][KS][BN][8];
  __shared__ int tokS[BM];
  __shared__ float wS[BM];

  if (tid < BM) {
    if constexpr (ROUTED) {
      tokS[tid] = listTok[(size_t)e * N_TOK + m0 + min(tid, rcnt - 1)];
      wS[tid] = (tid < rcnt) ? listW[(size_t)e * N_TOK + m0 + tid] : 0.f;
    } else { tokS[tid] = m0 + tid; wS[tid] = 1.f; }
  }
  __syncthreads();

  const int wid = tid >> 6, l = tid & 63;
  const int wm = wid >> 1, wn = wid & 1;
  const int lc = l & 15, hi = l >> 4;

  // ---- A source pointers (per lane) ----
  const unsigned short *pa0, *pa1;
  if constexpr (MODE < 2) {
    pa0 = Ab + (size_t)tokS[l] * DIM;
    pa1 = Ab + (size_t)tokS[64 + l] * DIM;
  } else if constexpr (ROUTED) {
    pa0 = Ab + (size_t)(rowbase + min(l, rcnt - 1)) * FDIM;
    pa1 = Ab + (size_t)(rowbase + min(64 + l, rcnt - 1)) * FDIM;
  } else {
    pa0 = nullptr; pa1 = nullptr;   // per-seg, computed in stage
  }

  // ---- B setup ----
  const float* bf_base = nullptr;
  const unsigned short *pb0 = nullptr, *pb1 = nullptr;
  if constexpr (ROUTED) {
    bf_base = Bf + (size_t)e * ((size_t)FDIM * DIM) + x0;  // DIM*FDIM == FDIM*DIM
  } else if constexpr (MODE < 2) {
    pb0 = Bt + (size_t)e * HSH * DIM + (size_t)(x0 + l) * DIM;
    pb1 = Bt + (size_t)e * HSH * DIM + (size_t)(x0 + 64 + l) * DIM;
  }

  // f32-staging thread mapping: thread owns plane k4a (8 k) x 4 f
  const int f4  = tid & 31;        // f group (4 cols)
  const int k4a = tid >> 5;        // plane 0..7
  f32x4 rB[2][4];                  // [s2 = k-half of plane][row j]

  auto stageIssue = [&](int g, int b) {
    const int seg = (NSEG > 1) ? (g / NT) : 0;
    const int d0 = (g - seg * NT) * BK;
    // A (async global -> LDS)
    if constexpr (MODE == 2 && !ROUTED) {
      const unsigned short* s0 = Ab + ((size_t)(seg * N_TOK + m0 + l)) * HSH + d0;
      const unsigned short* s1 = Ab + ((size_t)(seg * N_TOK + m0 + 64 + l)) * HSH + d0;
      gll16(s0 + (2 * wid) * 8,     &Al[b][2 * wid][0][0]);
      gll16(s1 + (2 * wid) * 8,     &Al[b][2 * wid][64][0]);
      gll16(s0 + (2 * wid + 1) * 8, &Al[b][2 * wid + 1][0][0]);
      gll16(s1 + (2 * wid + 1) * 8, &Al[b][2 * wid + 1][64][0]);
    } else {
      gll16(pa0 + d0 + (2 * wid) * 8,     &Al[b][2 * wid][0][0]);
      gll16(pa1 + d0 + (2 * wid) * 8,     &Al[b][2 * wid][64][0]);
      gll16(pa0 + d0 + (2 * wid + 1) * 8, &Al[b][2 * wid + 1][0][0]);
      gll16(pa1 + d0 + (2 * wid + 1) * 8, &Al[b][2 * wid + 1][64][0]);
    }
    // B
    if constexpr (ROUTED) {
      #pragma unroll
      for (int s2 = 0; s2 < 2; ++s2)
        #pragma unroll
        for (int j = 0; j < 4; ++j)
          rB[s2][j] = *reinterpret_cast<const f32x4*>(
              bf_base + (size_t)(d0 + k4a * 8 + s2 * 4 + j) * BSTR + f4 * 4);
    } else if constexpr (MODE < 2) {
      gll16(pb0 + d0 + (2 * wid) * 8,     &Bl[b][2 * wid][0][0]);
      gll16(pb1 + d0 + (2 * wid) * 8,     &Bl[b][2 * wid][64][0]);
      gll16(pb0 + d0 + (2 * wid + 1) * 8, &Bl[b][2 * wid + 1][0][0]);
      gll16(pb1 + d0 + (2 * wid + 1) * 8, &Bl[b][2 * wid + 1][64][0]);
    } else {
      const unsigned short* b0 = Bt + (size_t)seg * HSH * DIM + (size_t)(x0 + l) * HSH + d0;
      const unsigned short* b1 = Bt + (size_t)seg * HSH * DIM + (size_t)(x0 + 64 + l) * HSH + d0;
      gll16(b0 + (2 * wid) * 8,     &Bl[b][2 * wid][0][0]);
      gll16(b1 + (2 * wid) * 8,     &Bl[b][2 * wid][64][0]);
      gll16(b0 + (2 * wid + 1) * 8, &Bl[b][2 * wid + 1][0][0]);
      gll16(b1 + (2 * wid + 1) * 8, &Bl[b][2 * wid + 1][64][0]);
    }
  };

  auto stageWriteB = [&](int b) {
    if constexpr (ROUTED) {
      #pragma unroll
      for (int c = 0; c < 4; ++c) {
        u16x8 v;
        v[0] = f2b(rB[0][0][c]); v[1] = f2b(rB[0][1][c]);
        v[2] = f2b(rB[0][2][c]); v[3] = f2b(rB[0][3][c]);
        v[4] = f2b(rB[1][0][c]); v[5] = f2b(rB[1][1][c]);
        v[6] = f2b(rB[1][2][c]); v[7] = f2b(rB[1][3][c]);
        *reinterpret_cast<u16x8*>(&Bl[b][k4a][f4 * 4 + c][0]) = v;
      }
    }
  };

  f32x4 acc[4][4];
  #pragma unroll
  for (int i = 0; i < 4; ++i)
    #pragma unroll
    for (int j = 0; j < 4; ++j) acc[i][j] = f32x4{0.f, 0.f, 0.f, 0.f};

  // ---- pipeline ----
  int buf = 0;
  stageIssue(0, 0);
  __syncthreads();
  if constexpr (ROUTED) { stageWriteB(0); __syncthreads(); }

  for (int g = 0; g < TOT; ++g) {
    const int gn = (g + 1 < TOT) ? g + 1 : g;
    stageIssue(gn, buf ^ 1);
    // compute from buf
    #pragma unroll
    for (int ks = 0; ks < 2; ++ks) {
      bf16x8 af[4], bq[4];
      #pragma unroll
      for (int i = 0; i < 4; ++i)
        af[i] = *reinterpret_cast<const bf16x8*>(&Al[buf][ks * 4 + hi][wm * 64 + i * 16 + lc][0]);
      #pragma unroll
      for (int i = 0; i < 4; ++i)
        bq[i] = *reinterpret_cast<const bf16x8*>(&Bl[buf][ks * 4 + hi][wn * 64 + i * 16 + lc][0]);
      #pragma unroll
      for (int mi = 0; mi < 4; ++mi)
        #pragma unroll
        for (int ni = 0; ni < 4; ++ni)
          acc[mi][ni] = __builtin_amdgcn_mfma_f32_16x16x32_bf16(af[mi], bq[ni], acc[mi][ni], 0, 0, 0);
    }
    __syncthreads();
    if constexpr (ROUTED) { stageWriteB(buf ^ 1); __syncthreads(); }
    buf ^= 1;
  }

  // ---- epilogue ----
  #pragma unroll
  for (int mi = 0; mi < 4; ++mi)
    #pragma unroll
    for (int ni = 0; ni < 4; ++ni)
      #pragma unroll
      for (int r2 = 0; r2 < 4; ++r2) {
        const int row = wm * 64 + mi * 16 + hi * 4 + r2;
        if (row < rcnt) {
          const int col = x0 + wn * 64 + ni * 16 + lc;
          const float v = acc[mi][ni][r2];
          if constexpr (MODE == 0) {
            Hio[(size_t)(rowbase + row) * NOUT + col] = f2b(v);
          } else if constexpr (MODE == 1) {
            const size_t idx = (size_t)(rowbase + row) * NOUT + col;
            const float u = b2f(Hio[idx]);
            const float h = (v / (1.f + __expf(-v))) * u * wS[row];
            Hio[idx] = f2b(h);
          } else if constexpr (ROUTED) {
            atomicAdd(&outF[(size_t)tokS[row] * DIM + col], v);
          } else {
            outF[(size_t)(m0 + row) * DIM + col] = v;
          }
        }
      }
}

extern "C" void kernel_launch(void* const* d_in, const int* in_sizes, int n_in,
                              void* d_out, int out_size, void* d_ws, size_t ws_size,
                              hipStream_t stream) {
  const float* x   = (const float*)d_in[0];
  const float* rw  = (const float*)d_in[1];
  const float* rb  = (const float*)d_in[2];
  const float* wg  = (const float*)d_in[3];
  const float* wu  = (const float*)d_in[4];
  const float* wd  = (const float*)d_in[5];
  const float* swg = (const float*)d_in[6];
  const float* swu = (const float*)d_in[7];
  const float* swd = (const float*)d_in[8];
  float* out = (float*)d_out;
  char* ws = (char*)d_ws;

  int* cnt = (int*)ws;
  int* off = (int*)(ws + 256);
  int* listTok = (int*)(ws + 4096);
  float* listW = (float*)(ws + 4096 + 512 * 1024);
  unsigned short* xb   = (unsigned short*)(ws + (size_t) 2 * 1024 * 1024);  // 8 MB
  unsigned short* Hr   = (unsigned short*)(ws + (size_t)10 * 1024 * 1024);  // 8 MB
  unsigned short* Hs   = (unsigned short*)(ws + (size_t)18 * 1024 * 1024);  // 16 MB
  unsigned short* swuT = (unsigned short*)(ws + (size_t)34 * 1024 * 1024);  // 16 MB
  unsigned short* swgT = (unsigned short*)(ws + (size_t)50 * 1024 * 1024);  // 16 MB
  unsigned short* swdT = (unsigned short*)(ws + (size_t)66 * 1024 * 1024);  // -> 82 MB

  hipMemsetAsync(cnt, 0, NEXP * sizeof(int), stream);
  cvt_x_kernel<<<(N_TOK * DIM) / (256 * 8), 256, 0, stream>>>(x, xb);
  tr_shared_kernel<<<dim3(32, 32, 6), 256, 0, stream>>>(swu, swg, swd, swuT, swgT, swdT);
  router_kernel<<<N_TOK / 8, 256, 0, stream>>>(x, rw, rb, cnt, listTok, listW);
  scan_kernel<<<1, 64, 0, stream>>>(cnt, off);

  // routed experts
  gemm_kernel<0, true><<<dim3(FDIM / BN, NEXP, 16), 256, 0, stream>>>(
      xb, wu, nullptr, cnt, off, listTok, listW, Hr, nullptr);
  gemm_kernel<1, true><<<dim3(FDIM / BN, NEXP, 16), 256, 0, stream>>>(
      xb, wg, nullptr, cnt, off, listTok, listW, Hr, nullptr);
  // shared experts
  gemm_kernel<0, false><<<dim3(HSH / BN, NSH, N_TOK / BM), 256, 0, stream>>>(
      xb, nullptr, swuT, cnt, off, listTok, listW, Hs, nullptr);
  gemm_kernel<1, false><<<dim3(HSH / BN, NSH, N_TOK / BM), 256, 0, stream>>>(
      xb, nullptr, swgT, cnt, off, listTok, listW, Hs, nullptr);
  // down: shared writes out (both segments summed), routed accumulates atomically
  gemm_kernel<2, false><<<dim3(DIM / BN, 1, N_TOK / BM), 256, 0, stream>>>(
      Hs, nullptr, swdT, cnt, off, listTok, listW, nullptr, out);
  gemm_kernel<2, true><<<dim3(DIM / BN, NEXP, 16), 256, 0, stream>>>(
      Hr, wd, nullptr, cnt, off, listTok, listW, nullptr, out);
}

// Round 4
// 852.638 us; speedup vs baseline: 1.0451x; 1.0451x over previous
//
#include <hip/hip_runtime.h>
#include <hip/hip_bf16.h>

typedef __bf16 bf16x8 __attribute__((ext_vector_type(8)));
typedef float f32x4 __attribute__((ext_vector_type(4)));
typedef unsigned short u16x4 __attribute__((ext_vector_type(4)));
typedef unsigned short u16x8 __attribute__((ext_vector_type(8)));

#define DEVI __device__ __forceinline__

constexpr int N_TOK = 2048;   // B*T
constexpr int DIM   = 2048;   // D
constexpr int NEXP  = 64;     // E
constexpr int FDIM  = 512;    // F
constexpr int TOPK  = 4;      // K
constexpr int NSH   = 2;      // S
constexpr int HSH   = 2048;   // HS

constexpr int BM = 128, BN = 128, BK = 64, KS = 8;

DEVI unsigned short f2b(float f) {
  union { float fv; unsigned u; } v; v.fv = f;
  unsigned r = v.u + 0x7fffu + ((v.u >> 16) & 1u);
  return (unsigned short)(r >> 16);
}
DEVI float b2f(unsigned short h) {
  union { unsigned u; float f; } v; v.u = ((unsigned)h) << 16;
  return v.f;
}
DEVI void gll16(const void* g, void* l) {
  __builtin_amdgcn_global_load_lds((const __attribute__((address_space(1))) unsigned*)g,
                                   (__attribute__((address_space(3))) unsigned*)l, 16, 0, 0);
}

// ---------------- x -> bf16 ----------------
__global__ void cvt_x_kernel(const float* __restrict__ x, unsigned short* __restrict__ xb) {
  const size_t i = ((size_t)blockIdx.x * 256 + threadIdx.x) * 8;
  const float4 a = *reinterpret_cast<const float4*>(x + i);
  const float4 b = *reinterpret_cast<const float4*>(x + i + 4);
  u16x8 o;
  o[0] = f2b(a.x); o[1] = f2b(a.y); o[2] = f2b(a.z); o[3] = f2b(a.w);
  o[4] = f2b(b.x); o[5] = f2b(b.y); o[6] = f2b(b.z); o[7] = f2b(b.w);
  *reinterpret_cast<u16x8*>(xb + i) = o;
}

// ---------------- shared weights: transpose + bf16 ----------------
__global__ __launch_bounds__(256)
void tr_shared_kernel(const float* __restrict__ swu, const float* __restrict__ swg,
                      const float* __restrict__ swd, unsigned short* __restrict__ swuT,
                      unsigned short* __restrict__ swgT, unsigned short* __restrict__ swdT) {
  __shared__ float Lf[64][68];
  const int tid = threadIdx.x;
  const int r0 = blockIdx.x * 64, c0 = blockIdx.y * 64;
  const int z = blockIdx.z, mat = z >> 1;
  const size_t soff = (size_t)(z & 1) * DIM * HSH;
  const float* in = (mat == 0 ? swu : mat == 1 ? swg : swd) + soff;
  unsigned short* ot = (mat == 0 ? swuT : mat == 1 ? swgT : swdT) + soff;
  #pragma unroll
  for (int j = 0; j < 4; ++j) {
    const int idx = j * 1024 + tid * 4;
    const int row = idx >> 6, col = idx & 63;
    const float4 v = *reinterpret_cast<const float4*>(in + (size_t)(r0 + row) * 2048 + c0 + col);
    *reinterpret_cast<float4*>(&Lf[row][col]) = v;
  }
  __syncthreads();
  #pragma unroll
  for (int j = 0; j < 4; ++j) {
    const int idx = j * 1024 + tid * 4;
    const int orow = idx >> 6, ocol = idx & 63;
    u16x4 o;
    o[0] = f2b(Lf[ocol][orow]);     o[1] = f2b(Lf[ocol + 1][orow]);
    o[2] = f2b(Lf[ocol + 2][orow]); o[3] = f2b(Lf[ocol + 3][orow]);
    *reinterpret_cast<u16x4*>(ot + (size_t)(c0 + orow) * 2048 + r0 + ocol) = o;
  }
}

// ---------------- Router: LDS-staged x, coalesced rw ----------------
__global__ __launch_bounds__(256)
void router_kernel(const float* __restrict__ x, const float* __restrict__ rw,
                   const float* __restrict__ rb, int* __restrict__ cnt,
                   int* __restrict__ listTok, float* __restrict__ listW) {
  __shared__ float Lx[8][128];
  const int tid = threadIdx.x;
  const int lane = tid & 63;
  const int wave = tid >> 6;
  const int tokBase = blockIdx.x * 8;

  float acc0 = 0.f, acc1 = 0.f;
  for (int dc = 0; dc < DIM; dc += 128) {
    __syncthreads();
    {
      const int idx = tid * 4;
      const int row = idx >> 7, col = idx & 127;
      *reinterpret_cast<float4*>(&Lx[row][col]) =
          *reinterpret_cast<const float4*>(x + (size_t)(tokBase + row) * DIM + dc + col);
    }
    __syncthreads();
    #pragma unroll 16
    for (int dd = 0; dd < 128; ++dd) {
      const float r = rw[(size_t)(dc + dd) * NEXP + lane];
      acc0 = fmaf(Lx[wave * 2 + 0][dd], r, acc0);
      acc1 = fmaf(Lx[wave * 2 + 1][dd], r, acc1);
    }
  }

  const float bias = rb[lane];
  #pragma unroll
  for (int t = 0; t < 2; ++t) {
    const float v = (t == 0) ? acc0 : acc1;
    const int token = tokBase + wave * 2 + t;
    float m = v;
    #pragma unroll
    for (int o = 32; o > 0; o >>= 1) m = fmaxf(m, __shfl_xor(m, o));
    const float p = expf(v - m);
    float ss = p;
    #pragma unroll
    for (int o = 32; o > 0; o >>= 1) ss += __shfl_xor(ss, o);
    const float score = p / ss;
    float cur = v + bias;
    float wk[TOPK]; int ik[TOPK]; float wsum = 0.f;
    #pragma unroll
    for (int k = 0; k < TOPK; ++k) {
      float tm = cur;
      #pragma unroll
      for (int o = 32; o > 0; o >>= 1) tm = fmaxf(tm, __shfl_xor(tm, o));
      const unsigned long long msk = __ballot(cur == tm);
      const int sel = (int)__builtin_ctzll(msk);
      const float w = __shfl(score, sel);
      wk[k] = w; ik[k] = sel; wsum += w;
      if (lane == sel) cur = -3.4e38f;
    }
    if (lane < TOPK) {
      const int e = ik[lane];
      const float w = wk[lane] / wsum;
      const int slot = atomicAdd(&cnt[e], 1);
      listTok[(size_t)e * N_TOK + slot] = token;
      listW[(size_t)e * N_TOK + slot] = w;
    }
  }
}

__global__ void scan_kernel(const int* __restrict__ cnt, int* __restrict__ off) {
  if (threadIdx.x == 0) {
    int s = 0;
    for (int e = 0; e < NEXP; ++e) { off[e] = s; s += cnt[e]; }
  }
}

// ---------------- Unified GEMM ----------------
// MODE 0: U = A @ W            (write U bf16 into Hio)
// MODE 1: G = A @ W; H = silu(G)*U*wS  (read U from Hio, overwrite in place)
// MODE 2: out (+)= H @ Wd      (ROUTED: atomicAdd scatter; shared: direct store, 2 segs)
template<int MODE, bool ROUTED>
__global__ __launch_bounds__(256, 2)
void gemm_kernel(const unsigned short* __restrict__ Ab,
                 const float* __restrict__ Bf,
                 const unsigned short* __restrict__ Bt,
                 const int* __restrict__ cnt, const int* __restrict__ off,
                 const int* __restrict__ listTok, const float* __restrict__ listW,
                 unsigned short* __restrict__ Hio, float* __restrict__ outF) {
  constexpr int KSEG = (MODE < 2) ? DIM : (ROUTED ? FDIM : HSH);
  constexpr int NSEG = (MODE == 2 && !ROUTED) ? NSH : 1;
  constexpr int NOUT = (MODE < 2) ? (ROUTED ? FDIM : HSH) : DIM;
  constexpr int BSTR = (MODE < 2) ? FDIM : DIM;   // f32 weight row stride (routed)
  constexpr int NT = KSEG / BK, TOT = NSEG * NT;

  const int tid = threadIdx.x;
  const int x0 = blockIdx.x * BN;
  const int e  = blockIdx.y;
  const int m0 = blockIdx.z * BM;

  int rcnt = BM, rowbase;
  if constexpr (ROUTED) {
    const int c = cnt[e];
    if (m0 >= c) return;
    rcnt = min(BM, c - m0);
    rowbase = off[e] + m0;
  } else {
    rowbase = (MODE < 2) ? (e * N_TOK + m0) : m0;
  }

  __shared__ __align__(16) unsigned short Al[2][KS][BM][8];
  __shared__ __align__(16) unsigned short Bl[2][KS][BN][8];
  __shared__ int tokS[BM];
  __shared__ float wS[BM];

  if (tid < BM) {
    if constexpr (ROUTED) {
      tokS[tid] = listTok[(size_t)e * N_TOK + m0 + min(tid, rcnt - 1)];
      wS[tid] = (tid < rcnt) ? listW[(size_t)e * N_TOK + m0 + tid] : 0.f;
    } else { tokS[tid] = m0 + tid; wS[tid] = 1.f; }
  }
  __syncthreads();

  const int wid = tid >> 6, l = tid & 63;
  const int wm = wid >> 1, wn = wid & 1;
  const int lc = l & 15, hi = l >> 4;

  // ---- A source pointers (per lane) ----
  const unsigned short *pa0, *pa1;
  if constexpr (MODE < 2) {
    pa0 = Ab + (size_t)tokS[l] * DIM;
    pa1 = Ab + (size_t)tokS[64 + l] * DIM;
  } else if constexpr (ROUTED) {
    pa0 = Ab + (size_t)(rowbase + min(l, rcnt - 1)) * FDIM;
    pa1 = Ab + (size_t)(rowbase + min(64 + l, rcnt - 1)) * FDIM;
  } else {
    pa0 = nullptr; pa1 = nullptr;
  }

  // ---- B setup ----
  const float* bf_base = nullptr;
  const unsigned short *pb0 = nullptr, *pb1 = nullptr;
  if constexpr (ROUTED) {
    bf_base = Bf + (size_t)e * ((size_t)FDIM * DIM) + x0;
  } else if constexpr (MODE < 2) {
    pb0 = Bt + (size_t)e * HSH * DIM + (size_t)(x0 + l) * DIM;
    pb1 = Bt + (size_t)e * HSH * DIM + (size_t)(x0 + 64 + l) * DIM;
  }

  const int f4  = tid & 31;        // f group (4 cols)
  const int k4a = tid >> 5;        // plane 0..7
  f32x4 rB[2][4];

  auto stageIssue = [&](int g, int b) {
    const int seg = (NSEG > 1) ? (g / NT) : 0;
    const int d0 = (g - seg * NT) * BK;
    if constexpr (MODE == 2 && !ROUTED) {
      const unsigned short* s0 = Ab + ((size_t)(seg * N_TOK + m0 + l)) * HSH + d0;
      const unsigned short* s1 = Ab + ((size_t)(seg * N_TOK + m0 + 64 + l)) * HSH + d0;
      gll16(s0 + (2 * wid) * 8,     &Al[b][2 * wid][0][0]);
      gll16(s1 + (2 * wid) * 8,     &Al[b][2 * wid][64][0]);
      gll16(s0 + (2 * wid + 1) * 8, &Al[b][2 * wid + 1][0][0]);
      gll16(s1 + (2 * wid + 1) * 8, &Al[b][2 * wid + 1][64][0]);
    } else {
      gll16(pa0 + d0 + (2 * wid) * 8,     &Al[b][2 * wid][0][0]);
      gll16(pa1 + d0 + (2 * wid) * 8,     &Al[b][2 * wid][64][0]);
      gll16(pa0 + d0 + (2 * wid + 1) * 8, &Al[b][2 * wid + 1][0][0]);
      gll16(pa1 + d0 + (2 * wid + 1) * 8, &Al[b][2 * wid + 1][64][0]);
    }
    if constexpr (ROUTED) {
      #pragma unroll
      for (int s2 = 0; s2 < 2; ++s2)
        #pragma unroll
        for (int j = 0; j < 4; ++j)
          rB[s2][j] = *reinterpret_cast<const f32x4*>(
              bf_base + (size_t)(d0 + k4a * 8 + s2 * 4 + j) * BSTR + f4 * 4);
    } else if constexpr (MODE < 2) {
      gll16(pb0 + d0 + (2 * wid) * 8,     &Bl[b][2 * wid][0][0]);
      gll16(pb1 + d0 + (2 * wid) * 8,     &Bl[b][2 * wid][64][0]);
      gll16(pb0 + d0 + (2 * wid + 1) * 8, &Bl[b][2 * wid + 1][0][0]);
      gll16(pb1 + d0 + (2 * wid + 1) * 8, &Bl[b][2 * wid + 1][64][0]);
    } else {
      const unsigned short* b0 = Bt + (size_t)seg * HSH * DIM + (size_t)(x0 + l) * HSH + d0;
      const unsigned short* b1 = Bt + (size_t)seg * HSH * DIM + (size_t)(x0 + 64 + l) * HSH + d0;
      gll16(b0 + (2 * wid) * 8,     &Bl[b][2 * wid][0][0]);
      gll16(b1 + (2 * wid) * 8,     &Bl[b][2 * wid][64][0]);
      gll16(b0 + (2 * wid + 1) * 8, &Bl[b][2 * wid + 1][0][0]);
      gll16(b1 + (2 * wid + 1) * 8, &Bl[b][2 * wid + 1][64][0]);
    }
  };

  auto stageWriteB = [&](int b) {
    if constexpr (ROUTED) {
      #pragma unroll
      for (int c = 0; c < 4; ++c) {
        u16x8 v;
        v[0] = f2b(rB[0][0][c]); v[1] = f2b(rB[0][1][c]);
        v[2] = f2b(rB[0][2][c]); v[3] = f2b(rB[0][3][c]);
        v[4] = f2b(rB[1][0][c]); v[5] = f2b(rB[1][1][c]);
        v[6] = f2b(rB[1][2][c]); v[7] = f2b(rB[1][3][c]);
        *reinterpret_cast<u16x8*>(&Bl[b][k4a][f4 * 4 + c][0]) = v;
      }
    }
  };

  f32x4 acc[4][4];
  #pragma unroll
  for (int i = 0; i < 4; ++i)
    #pragma unroll
    for (int j = 0; j < 4; ++j) acc[i][j] = f32x4{0.f, 0.f, 0.f, 0.f};

  // ---- pipeline: 1 barrier per K-step ----
  int buf = 0;
  stageIssue(0, 0);
  stageWriteB(0);
  __syncthreads();

  for (int g = 0; g < TOT; ++g) {
    const int gn = (g + 1 < TOT) ? g + 1 : g;
    stageIssue(gn, buf ^ 1);
    #pragma unroll
    for (int ks = 0; ks < 2; ++ks) {
      bf16x8 af[4], bq[4];
      #pragma unroll
      for (int i = 0; i < 4; ++i)
        af[i] = *reinterpret_cast<const bf16x8*>(&Al[buf][ks * 4 + hi][wm * 64 + i * 16 + lc][0]);
      #pragma unroll
      for (int i = 0; i < 4; ++i)
        bq[i] = *reinterpret_cast<const bf16x8*>(&Bl[buf][ks * 4 + hi][wn * 64 + i * 16 + lc][0]);
      #pragma unroll
      for (int mi = 0; mi < 4; ++mi)
        #pragma unroll
        for (int ni = 0; ni < 4; ++ni)
          acc[mi][ni] = __builtin_amdgcn_mfma_f32_16x16x32_bf16(af[mi], bq[ni], acc[mi][ni], 0, 0, 0);
    }
    stageWriteB(buf ^ 1);
    __syncthreads();
    buf ^= 1;
  }

  // ---- epilogue ----
  #pragma unroll
  for (int mi = 0; mi < 4; ++mi)
    #pragma unroll
    for (int ni = 0; ni < 4; ++ni)
      #pragma unroll
      for (int r2 = 0; r2 < 4; ++r2) {
        const int row = wm * 64 + mi * 16 + hi * 4 + r2;
        if (row < rcnt) {
          const int col = x0 + wn * 64 + ni * 16 + lc;
          const float v = acc[mi][ni][r2];
          if constexpr (MODE == 0) {
            Hio[(size_t)(rowbase + row) * NOUT + col] = f2b(v);
          } else if constexpr (MODE == 1) {
            const size_t idx = (size_t)(rowbase + row) * NOUT + col;
            const float u = b2f(Hio[idx]);
            const float h = (v / (1.f + __expf(-v))) * u * wS[row];
            Hio[idx] = f2b(h);
          } else if constexpr (ROUTED) {
            atomicAdd(&outF[(size_t)tokS[row] * DIM + col], v);
          } else {
            outF[(size_t)(m0 + row) * DIM + col] = v;
          }
        }
      }
}

extern "C" void kernel_launch(void* const* d_in, const int* in_sizes, int n_in,
                              void* d_out, int out_size, void* d_ws, size_t ws_size,
                              hipStream_t stream) {
  const float* x   = (const float*)d_in[0];
  const float* rw  = (const float*)d_in[1];
  const float* rb  = (const float*)d_in[2];
  const float* wg  = (const float*)d_in[3];
  const float* wu  = (const float*)d_in[4];
  const float* wd  = (const float*)d_in[5];
  const float* swg = (const float*)d_in[6];
  const float* swu = (const float*)d_in[7];
  const float* swd = (const float*)d_in[8];
  float* out = (float*)d_out;
  char* ws = (char*)d_ws;

  int* cnt = (int*)ws;
  int* off = (int*)(ws + 256);
  int* listTok = (int*)(ws + 4096);
  float* listW = (float*)(ws + 4096 + 512 * 1024);
  unsigned short* xb   = (unsigned short*)(ws + (size_t) 2 * 1024 * 1024);  // 8 MB
  unsigned short* Hr   = (unsigned short*)(ws + (size_t)10 * 1024 * 1024);  // 8 MB
  unsigned short* Hs   = (unsigned short*)(ws + (size_t)18 * 1024 * 1024);  // 16 MB
  unsigned short* swuT = (unsigned short*)(ws + (size_t)34 * 1024 * 1024);  // 16 MB
  unsigned short* swgT = (unsigned short*)(ws + (size_t)50 * 1024 * 1024);  // 16 MB
  unsigned short* swdT = (unsigned short*)(ws + (size_t)66 * 1024 * 1024);  // -> 82 MB

  hipMemsetAsync(cnt, 0, NEXP * sizeof(int), stream);
  cvt_x_kernel<<<(N_TOK * DIM) / (256 * 8), 256, 0, stream>>>(x, xb);
  tr_shared_kernel<<<dim3(32, 32, 6), 256, 0, stream>>>(swu, swg, swd, swuT, swgT, swdT);
  router_kernel<<<N_TOK / 8, 256, 0, stream>>>(x, rw, rb, cnt, listTok, listW);
  scan_kernel<<<1, 64, 0, stream>>>(cnt, off);

  // routed experts
  gemm_kernel<0, true><<<dim3(FDIM / BN, NEXP, 16), 256, 0, stream>>>(
      xb, wu, nullptr, cnt, off, listTok, listW, Hr, nullptr);
  gemm_kernel<1, true><<<dim3(FDIM / BN, NEXP, 16), 256, 0, stream>>>(
      xb, wg, nullptr, cnt, off, listTok, listW, Hr, nullptr);
  // shared experts
  gemm_kernel<0, false><<<dim3(HSH / BN, NSH, N_TOK / BM), 256, 0, stream>>>(
      xb, nullptr, swuT, cnt, off, listTok, listW, Hs, nullptr);
  gemm_kernel<1, false><<<dim3(HSH / BN, NSH, N_TOK / BM), 256, 0, stream>>>(
      xb, nullptr, swgT, cnt, off, listTok, listW, Hs, nullptr);
  // down: shared writes out (both segments summed), routed accumulates atomically
  gemm_kernel<2, false><<<dim3(DIM / BN, 1, N_TOK / BM), 256, 0, stream>>>(
      Hs, nullptr, swdT, cnt, off, listTok, listW, nullptr, out);
  gemm_kernel<2, true><<<dim3(DIM / BN, NEXP, 16), 256, 0, stream>>>(
      Hr, wd, nullptr, cnt, off, listTok, listW, nullptr, out);
}

// Round 5
// 687.587 us; speedup vs baseline: 1.2959x; 1.2400x over previous
//
#include <hip/hip_runtime.h>
#include <hip/hip_bf16.h>

typedef __bf16 bf16x8 __attribute__((ext_vector_type(8)));
typedef float f32x4 __attribute__((ext_vector_type(4)));
typedef unsigned short u16x4 __attribute__((ext_vector_type(4)));
typedef unsigned short u16x8 __attribute__((ext_vector_type(8)));

#define DEVI __device__ __forceinline__

constexpr int N_TOK = 2048;   // B*T
constexpr int DIM   = 2048;   // D
constexpr int NEXP  = 64;     // E
constexpr int FDIM  = 512;    // F
constexpr int TOPK  = 4;      // K
constexpr int NSH   = 2;      // S
constexpr int HSH   = 2048;   // HS

constexpr int BK = 64, KS = 8;

DEVI unsigned short f2b(float f) {
  union { float fv; unsigned u; } v; v.fv = f;
  unsigned r = v.u + 0x7fffu + ((v.u >> 16) & 1u);
  return (unsigned short)(r >> 16);
}
DEVI float b2f(unsigned short h) {
  union { unsigned u; float f; } v; v.u = ((unsigned)h) << 16;
  return v.f;
}
DEVI void gll16(const void* g, void* l) {
  __builtin_amdgcn_global_load_lds((const __attribute__((address_space(1))) unsigned*)g,
                                   (__attribute__((address_space(3))) unsigned*)l, 16, 0, 0);
}

// ---------------- x -> bf16 ----------------
__global__ void cvt_x_kernel(const float* __restrict__ x, unsigned short* __restrict__ xb) {
  const size_t i = ((size_t)blockIdx.x * 256 + threadIdx.x) * 8;
  const float4 a = *reinterpret_cast<const float4*>(x + i);
  const float4 b = *reinterpret_cast<const float4*>(x + i + 4);
  u16x8 o;
  o[0] = f2b(a.x); o[1] = f2b(a.y); o[2] = f2b(a.z); o[3] = f2b(a.w);
  o[4] = f2b(b.x); o[5] = f2b(b.y); o[6] = f2b(b.z); o[7] = f2b(b.w);
  *reinterpret_cast<u16x8*>(xb + i) = o;
}

// ---------------- shared weights: transpose + bf16 ----------------
__global__ __launch_bounds__(256)
void tr_shared_kernel(const float* __restrict__ swu, const float* __restrict__ swg,
                      const float* __restrict__ swd, unsigned short* __restrict__ swuT,
                      unsigned short* __restrict__ swgT, unsigned short* __restrict__ swdT) {
  __shared__ float Lf[64][68];
  const int tid = threadIdx.x;
  const int r0 = blockIdx.x * 64, c0 = blockIdx.y * 64;
  const int z = blockIdx.z, mat = z >> 1;
  const size_t soff = (size_t)(z & 1) * DIM * HSH;
  const float* in = (mat == 0 ? swu : mat == 1 ? swg : swd) + soff;
  unsigned short* ot = (mat == 0 ? swuT : mat == 1 ? swgT : swdT) + soff;
  #pragma unroll
  for (int j = 0; j < 4; ++j) {
    const int idx = j * 1024 + tid * 4;
    const int row = idx >> 6, col = idx & 63;
    const float4 v = *reinterpret_cast<const float4*>(in + (size_t)(r0 + row) * 2048 + c0 + col);
    *reinterpret_cast<float4*>(&Lf[row][col]) = v;
  }
  __syncthreads();
  #pragma unroll
  for (int j = 0; j < 4; ++j) {
    const int idx = j * 1024 + tid * 4;
    const int orow = idx >> 6, ocol = idx & 63;
    u16x4 o;
    o[0] = f2b(Lf[ocol][orow]);     o[1] = f2b(Lf[ocol + 1][orow]);
    o[2] = f2b(Lf[ocol + 2][orow]); o[3] = f2b(Lf[ocol + 3][orow]);
    *reinterpret_cast<u16x4*>(ot + (size_t)(c0 + orow) * 2048 + r0 + ocol) = o;
  }
}

// ---------------- Router ----------------
__global__ __launch_bounds__(256)
void router_kernel(const float* __restrict__ x, const float* __restrict__ rw,
                   const float* __restrict__ rb, int* __restrict__ cnt,
                   int* __restrict__ listTok, float* __restrict__ listW) {
  __shared__ float Lx[8][128];
  const int tid = threadIdx.x;
  const int lane = tid & 63;
  const int wave = tid >> 6;
  const int tokBase = blockIdx.x * 8;

  float acc0 = 0.f, acc1 = 0.f;
  for (int dc = 0; dc < DIM; dc += 128) {
    __syncthreads();
    {
      const int idx = tid * 4;
      const int row = idx >> 7, col = idx & 127;
      *reinterpret_cast<float4*>(&Lx[row][col]) =
          *reinterpret_cast<const float4*>(x + (size_t)(tokBase + row) * DIM + dc + col);
    }
    __syncthreads();
    #pragma unroll 16
    for (int dd = 0; dd < 128; ++dd) {
      const float r = rw[(size_t)(dc + dd) * NEXP + lane];
      acc0 = fmaf(Lx[wave * 2 + 0][dd], r, acc0);
      acc1 = fmaf(Lx[wave * 2 + 1][dd], r, acc1);
    }
  }

  const float bias = rb[lane];
  #pragma unroll
  for (int t = 0; t < 2; ++t) {
    const float v = (t == 0) ? acc0 : acc1;
    const int token = tokBase + wave * 2 + t;
    float m = v;
    #pragma unroll
    for (int o = 32; o > 0; o >>= 1) m = fmaxf(m, __shfl_xor(m, o));
    const float p = expf(v - m);
    float ss = p;
    #pragma unroll
    for (int o = 32; o > 0; o >>= 1) ss += __shfl_xor(ss, o);
    const float score = p / ss;
    float cur = v + bias;
    float wk[TOPK]; int ik[TOPK]; float wsum = 0.f;
    #pragma unroll
    for (int k = 0; k < TOPK; ++k) {
      float tm = cur;
      #pragma unroll
      for (int o = 32; o > 0; o >>= 1) tm = fmaxf(tm, __shfl_xor(tm, o));
      const unsigned long long msk = __ballot(cur == tm);
      const int sel = (int)__builtin_ctzll(msk);
      const float w = __shfl(score, sel);
      wk[k] = w; ik[k] = sel; wsum += w;
      if (lane == sel) cur = -3.4e38f;
    }
    if (lane < TOPK) {
      const int e = ik[lane];
      const float w = wk[lane] / wsum;
      const int slot = atomicAdd(&cnt[e], 1);
      listTok[(size_t)e * N_TOK + slot] = token;
      listW[(size_t)e * N_TOK + slot] = w;
    }
  }
}

__global__ void scan_kernel(const int* __restrict__ cnt, int* __restrict__ off) {
  if (threadIdx.x == 0) {
    int s = 0;
    for (int e = 0; e < NEXP; ++e) { off[e] = s; s += cnt[e]; }
  }
}

// ---------------- Routed up: GPASS=0 -> U, GPASS=1 -> H=silu(G)*U*w ----------------
template<bool GPASS>
__global__ __launch_bounds__(256, 2)
void up_routed(const unsigned short* __restrict__ xb, const float* __restrict__ W,
               const int* __restrict__ cnt, const int* __restrict__ off,
               const int* __restrict__ listTok, const float* __restrict__ listW,
               unsigned short* __restrict__ H) {
  const int tid = threadIdx.x;
  const int f0 = blockIdx.x * 128;
  const int e  = blockIdx.y;
  const int m0 = blockIdx.z * 128;
  const int c = cnt[e];
  if (m0 >= c) return;
  const int rcnt = min(128, c - m0);
  const int rowbase = off[e] + m0;

  __shared__ __align__(16) unsigned short Al[KS][128][8];
  __shared__ __align__(16) unsigned short Bl[KS][128][8];
  __shared__ int tokS[128];
  __shared__ float wS[128];

  if (tid < 128) {
    tokS[tid] = listTok[(size_t)e * N_TOK + m0 + min(tid, rcnt - 1)];
    wS[tid] = (tid < rcnt) ? listW[(size_t)e * N_TOK + m0 + tid] : 0.f;
  }
  __syncthreads();

  const int wid = tid >> 6, l = tid & 63;
  const int wm = wid >> 1, wn = wid & 1;
  const int lc = l & 15, hi = l >> 4;

  const unsigned short* pa0 = xb + (size_t)tokS[l] * DIM;
  const unsigned short* pa1 = xb + (size_t)tokS[64 + l] * DIM;
  const float* bw = W + (size_t)e * DIM * FDIM + f0;
  const int f4 = tid & 31, k4a = tid >> 5;

  f32x4 acc[4][4];
  #pragma unroll
  for (int i = 0; i < 4; ++i)
    #pragma unroll
    for (int j = 0; j < 4; ++j) acc[i][j] = f32x4{0.f, 0.f, 0.f, 0.f};

  for (int d0 = 0; d0 < DIM; d0 += BK) {
    gll16(pa0 + d0 + (2 * wid) * 8,     &Al[2 * wid][0][0]);
    gll16(pa1 + d0 + (2 * wid) * 8,     &Al[2 * wid][64][0]);
    gll16(pa0 + d0 + (2 * wid + 1) * 8, &Al[2 * wid + 1][0][0]);
    gll16(pa1 + d0 + (2 * wid + 1) * 8, &Al[2 * wid + 1][64][0]);
    f32x4 rB[2][4];
    #pragma unroll
    for (int s2 = 0; s2 < 2; ++s2)
      #pragma unroll
      for (int j = 0; j < 4; ++j)
        rB[s2][j] = *reinterpret_cast<const f32x4*>(
            bw + (size_t)(d0 + k4a * 8 + s2 * 4 + j) * FDIM + f4 * 4);
    #pragma unroll
    for (int cc = 0; cc < 4; ++cc) {
      u16x8 v;
      v[0] = f2b(rB[0][0][cc]); v[1] = f2b(rB[0][1][cc]);
      v[2] = f2b(rB[0][2][cc]); v[3] = f2b(rB[0][3][cc]);
      v[4] = f2b(rB[1][0][cc]); v[5] = f2b(rB[1][1][cc]);
      v[6] = f2b(rB[1][2][cc]); v[7] = f2b(rB[1][3][cc]);
      *reinterpret_cast<u16x8*>(&Bl[k4a][f4 * 4 + cc][0]) = v;
    }
    __syncthreads();
    #pragma unroll
    for (int ks = 0; ks < 2; ++ks) {
      bf16x8 af[4], bq[4];
      #pragma unroll
      for (int i = 0; i < 4; ++i)
        af[i] = *reinterpret_cast<const bf16x8*>(&Al[ks * 4 + hi][wm * 64 + i * 16 + lc][0]);
      #pragma unroll
      for (int i = 0; i < 4; ++i)
        bq[i] = *reinterpret_cast<const bf16x8*>(&Bl[ks * 4 + hi][wn * 64 + i * 16 + lc][0]);
      #pragma unroll
      for (int mi = 0; mi < 4; ++mi)
        #pragma unroll
        for (int ni = 0; ni < 4; ++ni)
          acc[mi][ni] = __builtin_amdgcn_mfma_f32_16x16x32_bf16(af[mi], bq[ni], acc[mi][ni], 0, 0, 0);
    }
    __syncthreads();
  }

  #pragma unroll
  for (int mi = 0; mi < 4; ++mi)
    #pragma unroll
    for (int ni = 0; ni < 4; ++ni)
      #pragma unroll
      for (int r2 = 0; r2 < 4; ++r2) {
        const int row = wm * 64 + mi * 16 + hi * 4 + r2;
        if (row < rcnt) {
          const int col = f0 + wn * 64 + ni * 16 + lc;
          const size_t idx = (size_t)(rowbase + row) * FDIM + col;
          const float v = acc[mi][ni][r2];
          if constexpr (GPASS) {
            const float u = b2f(H[idx]);
            H[idx] = f2b((v / (1.f + __expf(-v))) * u * wS[row]);
          } else {
            H[idx] = f2b(v);
          }
        }
      }
}

// ---------------- Shared up (fused U+G): BM=128, BN=64 ----------------
__global__ __launch_bounds__(256, 2)
void up_shared(const unsigned short* __restrict__ xb,
               const unsigned short* __restrict__ WuT, const unsigned short* __restrict__ WgT,
               unsigned short* __restrict__ H) {
  const int tid = threadIdx.x;
  const int f0 = blockIdx.x * 64;
  const int s  = blockIdx.y;
  const int m0 = blockIdx.z * 128;

  __shared__ __align__(16) unsigned short Al[KS][128][8];
  __shared__ __align__(16) unsigned short Bu[KS][64][8];
  __shared__ __align__(16) unsigned short Bg[KS][64][8];

  const int wid = tid >> 6, l = tid & 63;
  const int wm = wid >> 1, wn = wid & 1;
  const int lc = l & 15, hi = l >> 4;

  const unsigned short* pa0 = xb + (size_t)(m0 + l) * DIM;
  const unsigned short* pa1 = xb + (size_t)(m0 + 64 + l) * DIM;
  const unsigned short* pbu = WuT + (size_t)s * HSH * DIM + (size_t)(f0 + l) * DIM;
  const unsigned short* pbg = WgT + (size_t)s * HSH * DIM + (size_t)(f0 + l) * DIM;

  f32x4 aU[4][2], aG[4][2];
  #pragma unroll
  for (int i = 0; i < 4; ++i)
    #pragma unroll
    for (int j = 0; j < 2; ++j) { aU[i][j] = f32x4{0.f,0.f,0.f,0.f}; aG[i][j] = f32x4{0.f,0.f,0.f,0.f}; }

  for (int d0 = 0; d0 < DIM; d0 += BK) {
    gll16(pa0 + d0 + (2 * wid) * 8,     &Al[2 * wid][0][0]);
    gll16(pa1 + d0 + (2 * wid) * 8,     &Al[2 * wid][64][0]);
    gll16(pa0 + d0 + (2 * wid + 1) * 8, &Al[2 * wid + 1][0][0]);
    gll16(pa1 + d0 + (2 * wid + 1) * 8, &Al[2 * wid + 1][64][0]);
    gll16(pbu + d0 + (2 * wid) * 8,     &Bu[2 * wid][0][0]);
    gll16(pbu + d0 + (2 * wid + 1) * 8, &Bu[2 * wid + 1][0][0]);
    gll16(pbg + d0 + (2 * wid) * 8,     &Bg[2 * wid][0][0]);
    gll16(pbg + d0 + (2 * wid + 1) * 8, &Bg[2 * wid + 1][0][0]);
    __syncthreads();
    #pragma unroll
    for (int ks = 0; ks < 2; ++ks) {
      bf16x8 af[4], bu[2], bg[2];
      #pragma unroll
      for (int i = 0; i < 4; ++i)
        af[i] = *reinterpret_cast<const bf16x8*>(&Al[ks * 4 + hi][wm * 64 + i * 16 + lc][0]);
      #pragma unroll
      for (int i = 0; i < 2; ++i) {
        bu[i] = *reinterpret_cast<const bf16x8*>(&Bu[ks * 4 + hi][wn * 32 + i * 16 + lc][0]);
        bg[i] = *reinterpret_cast<const bf16x8*>(&Bg[ks * 4 + hi][wn * 32 + i * 16 + lc][0]);
      }
      #pragma unroll
      for (int mi = 0; mi < 4; ++mi)
        #pragma unroll
        for (int ni = 0; ni < 2; ++ni) {
          aU[mi][ni] = __builtin_amdgcn_mfma_f32_16x16x32_bf16(af[mi], bu[ni], aU[mi][ni], 0, 0, 0);
          aG[mi][ni] = __builtin_amdgcn_mfma_f32_16x16x32_bf16(af[mi], bg[ni], aG[mi][ni], 0, 0, 0);
        }
    }
    __syncthreads();
  }

  #pragma unroll
  for (int mi = 0; mi < 4; ++mi)
    #pragma unroll
    for (int ni = 0; ni < 2; ++ni)
      #pragma unroll
      for (int r2 = 0; r2 < 4; ++r2) {
        const int row = wm * 64 + mi * 16 + hi * 4 + r2;
        const int col = f0 + wn * 32 + ni * 16 + lc;
        const float g = aG[mi][ni][r2], u = aU[mi][ni][r2];
        const float h = (g / (1.f + __expf(-g))) * u;
        H[((size_t)s * N_TOK + m0 + row) * HSH + col] = f2b(h);
      }
}

// ---------------- Merged down: out += H @ Wd (all atomic; y<64 routed, y=64,65 shared segs) ----------------
__global__ __launch_bounds__(256, 2)
void down_all(const unsigned short* __restrict__ Hr, const unsigned short* __restrict__ Hs,
              const float* __restrict__ wd, const unsigned short* __restrict__ swdT,
              const int* __restrict__ cnt, const int* __restrict__ off,
              const int* __restrict__ listTok, float* __restrict__ out) {
  const int tid = threadIdx.x;
  const int x0 = blockIdx.x * 128;
  const int y  = blockIdx.y;
  const int m0 = blockIdx.z * 128;
  const bool routed = y < NEXP;

  __shared__ __align__(16) unsigned short Al[KS][128][8];
  __shared__ __align__(16) unsigned short Bl[KS][128][8];
  __shared__ int tokS[128];

  const int wid = tid >> 6, l = tid & 63;
  const int wm = wid >> 1, wn = wid & 1;
  const int lc = l & 15, hi = l >> 4;

  int rcnt = 128, Kd;
  const unsigned short *pa0, *pa1, *pb0 = nullptr, *pb1 = nullptr;
  const float* bw = nullptr;

  if (routed) {
    const int c = cnt[y];
    if (m0 >= c) return;
    rcnt = min(128, c - m0);
    const int rowbase = off[y] + m0;
    Kd = FDIM;
    if (tid < 128) tokS[tid] = listTok[(size_t)y * N_TOK + m0 + min(tid, rcnt - 1)];
    pa0 = Hr + (size_t)(rowbase + min(l, rcnt - 1)) * FDIM;
    pa1 = Hr + (size_t)(rowbase + min(64 + l, rcnt - 1)) * FDIM;
    bw = wd + (size_t)y * FDIM * DIM + x0;
  } else {
    const int s = y - NEXP;
    Kd = HSH;
    if (tid < 128) tokS[tid] = m0 + tid;
    pa0 = Hs + ((size_t)s * N_TOK + m0 + l) * HSH;
    pa1 = Hs + ((size_t)s * N_TOK + m0 + 64 + l) * HSH;
    pb0 = swdT + (size_t)s * HSH * DIM + (size_t)(x0 + l) * HSH;
    pb1 = swdT + (size_t)s * HSH * DIM + (size_t)(x0 + 64 + l) * HSH;
  }

  const int f4 = tid & 31, k4a = tid >> 5;

  f32x4 acc[4][4];
  #pragma unroll
  for (int i = 0; i < 4; ++i)
    #pragma unroll
    for (int j = 0; j < 4; ++j) acc[i][j] = f32x4{0.f, 0.f, 0.f, 0.f};

  for (int d0 = 0; d0 < Kd; d0 += BK) {
    gll16(pa0 + d0 + (2 * wid) * 8,     &Al[2 * wid][0][0]);
    gll16(pa1 + d0 + (2 * wid) * 8,     &Al[2 * wid][64][0]);
    gll16(pa0 + d0 + (2 * wid + 1) * 8, &Al[2 * wid + 1][0][0]);
    gll16(pa1 + d0 + (2 * wid + 1) * 8, &Al[2 * wid + 1][64][0]);
    if (routed) {
      f32x4 rB[2][4];
      #pragma unroll
      for (int s2 = 0; s2 < 2; ++s2)
        #pragma unroll
        for (int j = 0; j < 4; ++j)
          rB[s2][j] = *reinterpret_cast<const f32x4*>(
              bw + (size_t)(d0 + k4a * 8 + s2 * 4 + j) * DIM + f4 * 4);
      #pragma unroll
      for (int cc = 0; cc < 4; ++cc) {
        u16x8 v;
        v[0] = f2b(rB[0][0][cc]); v[1] = f2b(rB[0][1][cc]);
        v[2] = f2b(rB[0][2][cc]); v[3] = f2b(rB[0][3][cc]);
        v[4] = f2b(rB[1][0][cc]); v[5] = f2b(rB[1][1][cc]);
        v[6] = f2b(rB[1][2][cc]); v[7] = f2b(rB[1][3][cc]);
        *reinterpret_cast<u16x8*>(&Bl[k4a][f4 * 4 + cc][0]) = v;
      }
    } else {
      gll16(pb0 + d0 + (2 * wid) * 8,     &Bl[2 * wid][0][0]);
      gll16(pb1 + d0 + (2 * wid) * 8,     &Bl[2 * wid][64][0]);
      gll16(pb0 + d0 + (2 * wid + 1) * 8, &Bl[2 * wid + 1][0][0]);
      gll16(pb1 + d0 + (2 * wid + 1) * 8, &Bl[2 * wid + 1][64][0]);
    }
    __syncthreads();
    #pragma unroll
    for (int ks = 0; ks < 2; ++ks) {
      bf16x8 af[4], bq[4];
      #pragma unroll
      for (int i = 0; i < 4; ++i)
        af[i] = *reinterpret_cast<const bf16x8*>(&Al[ks * 4 + hi][wm * 64 + i * 16 + lc][0]);
      #pragma unroll
      for (int i = 0; i < 4; ++i)
        bq[i] = *reinterpret_cast<const bf16x8*>(&Bl[ks * 4 + hi][wn * 64 + i * 16 + lc][0]);
      #pragma unroll
      for (int mi = 0; mi < 4; ++mi)
        #pragma unroll
        for (int ni = 0; ni < 4; ++ni)
          acc[mi][ni] = __builtin_amdgcn_mfma_f32_16x16x32_bf16(af[mi], bq[ni], acc[mi][ni], 0, 0, 0);
    }
    __syncthreads();
  }

  #pragma unroll
  for (int mi = 0; mi < 4; ++mi)
    #pragma unroll
    for (int ni = 0; ni < 4; ++ni)
      #pragma unroll
      for (int r2 = 0; r2 < 4; ++r2) {
        const int row = wm * 64 + mi * 16 + hi * 4 + r2;
        if (row < rcnt) {
          const int col = x0 + wn * 64 + ni * 16 + lc;
          atomicAdd(&out[(size_t)tokS[row] * DIM + col], acc[mi][ni][r2]);
        }
      }
}

extern "C" void kernel_launch(void* const* d_in, const int* in_sizes, int n_in,
                              void* d_out, int out_size, void* d_ws, size_t ws_size,
                              hipStream_t stream) {
  const float* x   = (const float*)d_in[0];
  const float* rw  = (const float*)d_in[1];
  const float* rb  = (const float*)d_in[2];
  const float* wg  = (const float*)d_in[3];
  const float* wu  = (const float*)d_in[4];
  const float* wd  = (const float*)d_in[5];
  const float* swg = (const float*)d_in[6];
  const float* swu = (const float*)d_in[7];
  const float* swd = (const float*)d_in[8];
  float* out = (float*)d_out;
  char* ws = (char*)d_ws;

  int* cnt = (int*)ws;
  int* off = (int*)(ws + 256);
  int* listTok = (int*)(ws + 4096);
  float* listW = (float*)(ws + 4096 + 512 * 1024);
  unsigned short* xb   = (unsigned short*)(ws + (size_t) 2 * 1024 * 1024);  // 8 MB
  unsigned short* Hr   = (unsigned short*)(ws + (size_t)10 * 1024 * 1024);  // 8 MB
  unsigned short* Hs   = (unsigned short*)(ws + (size_t)18 * 1024 * 1024);  // 16 MB
  unsigned short* swuT = (unsigned short*)(ws + (size_t)34 * 1024 * 1024);  // 16 MB
  unsigned short* swgT = (unsigned short*)(ws + (size_t)50 * 1024 * 1024);  // 16 MB
  unsigned short* swdT = (unsigned short*)(ws + (size_t)66 * 1024 * 1024);  // -> 82 MB

  hipMemsetAsync(cnt, 0, NEXP * sizeof(int), stream);
  hipMemsetAsync(out, 0, (size_t)N_TOK * DIM * sizeof(float), stream);
  cvt_x_kernel<<<(N_TOK * DIM) / (256 * 8), 256, 0, stream>>>(x, xb);
  tr_shared_kernel<<<dim3(32, 32, 6), 256, 0, stream>>>(swu, swg, swd, swuT, swgT, swdT);
  router_kernel<<<N_TOK / 8, 256, 0, stream>>>(x, rw, rb, cnt, listTok, listW);
  scan_kernel<<<1, 64, 0, stream>>>(cnt, off);

  up_routed<false><<<dim3(FDIM / 128, NEXP, 16), 256, 0, stream>>>(
      xb, wu, cnt, off, listTok, listW, Hr);
  up_routed<true><<<dim3(FDIM / 128, NEXP, 16), 256, 0, stream>>>(
      xb, wg, cnt, off, listTok, listW, Hr);
  up_shared<<<dim3(HSH / 64, NSH, N_TOK / 128), 256, 0, stream>>>(
      xb, swuT, swgT, Hs);
  down_all<<<dim3(DIM / 128, NEXP + NSH, 16), 256, 0, stream>>>(
      Hr, Hs, wd, swdT, cnt, off, listTok, out);
}